// Round 6
// baseline (167.765 us; speedup 1.0000x reference)
//
#include <hip/hip_runtime.h>

// Problem constants (fixed by setup_inputs): B=256, J=17, H*W=3072.
#define HW          3072
#define N_TOTAL     (256 * 17 * 3072)     // 13,369,344 elements
#define NJOINTS     (256 * 17)            // 4352 (b,j) slots, each with one weight
#define F4_PER_J    (HW / 4)              // 768 float4s per joint
#define BLOCK       256
#define NBLOCKS1    NJOINTS               // 1 joint per block: 4352 = 17 * 256 CUs exact
#define ITERS_PER_J (F4_PER_J / BLOCK)    // 3 float4s per thread

// Fused single-kernel design (diagnostic round established):
//  - k1 is ~20us vs a ~14-17us HBM floor; k2 (~3us) + its launch gap are pure
//    overhead -> fold the final reduction into k1 with one float atomicAdd
//    per block into d_out[0] (zeroed by a 4B memset node in the graph).
//  - 4352 blocks = exactly 17 blocks/CU: no half-pass tail (was 8.5/CU).
//  - WRITE_SIZE==68KB in the probe refuted the poison-writeback theory; NT
//    scalar loads are measured-neutral and infra-proven, so they stay.
//  - atomicAdd ordering perturbs the loss by O(1 ulp of 0.04) ~ 1e-8.
__global__ __launch_bounds__(BLOCK) void fused_sse_kernel(
    const float* __restrict__ out,
    const float* __restrict__ tgt,
    const float* __restrict__ tw,
    float* __restrict__ loss)
{
    const int tid = threadIdx.x;
    const int j   = blockIdx.x;             // flat (b*17 + joint) index

    const float w  = tw[j];                 // block-uniform -> scalar load
    const float w2 = w * w;

    float s = 0.0f;
    #pragma unroll
    for (int k = 0; k < ITERS_PER_J; ++k) {
        const int e = (j * F4_PER_J + k * BLOCK + tid) * 4;
        float o0 = __builtin_nontemporal_load(out + e + 0);
        float o1 = __builtin_nontemporal_load(out + e + 1);
        float o2 = __builtin_nontemporal_load(out + e + 2);
        float o3 = __builtin_nontemporal_load(out + e + 3);
        float t0 = __builtin_nontemporal_load(tgt + e + 0);
        float t1 = __builtin_nontemporal_load(tgt + e + 1);
        float t2 = __builtin_nontemporal_load(tgt + e + 2);
        float t3 = __builtin_nontemporal_load(tgt + e + 3);
        float d0 = o0 - t0;
        float d1 = o1 - t1;
        float d2 = o2 - t2;
        float d3 = o3 - t3;
        s += d0 * d0 + d1 * d1 + d2 * d2 + d3 * d3;
    }
    float acc = w2 * s;

    // wave64 shuffle reduction
    #pragma unroll
    for (int off = 32; off > 0; off >>= 1)
        acc += __shfl_down(acc, off, 64);

    __shared__ float lds[BLOCK / 64];
    int lane = threadIdx.x & 63;
    int wave = threadIdx.x >> 6;
    if (lane == 0) lds[wave] = acc;
    __syncthreads();

    if (threadIdx.x == 0) {
        float bsum = 0.0f;
        #pragma unroll
        for (int w_i = 0; w_i < BLOCK / 64; ++w_i) bsum += lds[w_i];
        // Pre-scale so the atomic accumulates the final loss directly.
        atomicAdd(loss, bsum * (0.5f / (float)N_TOTAL));
    }
}

extern "C" void kernel_launch(void* const* d_in, const int* in_sizes, int n_in,
                              void* d_out, int out_size, void* d_ws, size_t ws_size,
                              hipStream_t stream)
{
    const float* output = (const float*)d_in[0];   // [256,17,64,48] f32
    const float* target = (const float*)d_in[1];   // [256,17,64,48] f32
    const float* tw     = (const float*)d_in[2];   // [256,17,1]     f32

    // Zero the 4-byte accumulator (graph-capturable memset node; the harness
    // itself enqueues hipMemsetAsync during reset, so this is capture-safe).
    hipMemsetAsync(d_out, 0, sizeof(float), stream);

    fused_sse_kernel<<<NBLOCKS1, BLOCK, 0, stream>>>(output, target, tw,
                                                     (float*)d_out);
}

// Round 7
// 123.153 us; speedup vs baseline: 1.3623x; 1.3623x over previous
//
#include <hip/hip_runtime.h>

// Problem constants (fixed by setup_inputs): B=256, J=17, H*W=3072.
#define HW          3072
#define N_TOTAL     (256 * 17 * 3072)     // 13,369,344 elements
#define NJOINTS     (256 * 17)            // 4352 (b,j) slots, each with one weight
#define F4_PER_J    (HW / 4)              // 768 float4s per joint
#define BLOCK       256
#define JPB         2                     // joints per block
#define NBLOCKS1    (NJOINTS / JPB)       // 2176 blocks (8.5/CU, 94% tail eff.)

// Round-6 post-mortem drove this design:
//  - Fused atomicAdd version: 62us, VGPR=16, VALUBusy 3% -> (a) 4352
//    same-address device atomics serialize (~14ns each = the whole 62us),
//    (b) scalar-NT loads at low reg pressure compiled to SERIAL load-use
//    chains (VGPR=16 can't hold 6 dwordx4 in flight). Both reverted.
//  - This version maximizes MLP explicitly: all 12 float4 loads issued
//    into separately-named registers BEFORE any arithmetic -> 12
//    back-to-back global_load_dwordx4 per thread (~48 payload VGPRs).
//  - Plain float4 loads (round-0-proven infra-safe form). No NT: measured
//    neutral, and L3 retention actually HELPS (52MB of 107MB was L3-hit).
//  - Two-kernel reduction: partials + tiny final reduce. No atomics.
__global__ __launch_bounds__(BLOCK) void partial_sse_kernel(
    const float* __restrict__ out,
    const float* __restrict__ tgt,
    const float* __restrict__ tw,
    float* __restrict__ partials)
{
    const float4* __restrict__ o4 = (const float4*)out;
    const float4* __restrict__ t4 = (const float4*)tgt;

    const int tid  = threadIdx.x;
    const int j0   = blockIdx.x * JPB;
    const int base = j0 * F4_PER_J + tid;       // joint j0, k=0 slot

    // Issue ALL 12 loads back-to-back (6 per stream: 2 joints x 3 chunks).
    float4 a0 = o4[base + 0 * BLOCK];
    float4 a1 = o4[base + 1 * BLOCK];
    float4 a2 = o4[base + 2 * BLOCK];
    float4 a3 = o4[base + 3 * BLOCK];           // joint j0+1 starts at +768
    float4 a4 = o4[base + 4 * BLOCK];
    float4 a5 = o4[base + 5 * BLOCK];
    float4 b0 = t4[base + 0 * BLOCK];
    float4 b1 = t4[base + 1 * BLOCK];
    float4 b2 = t4[base + 2 * BLOCK];
    float4 b3 = t4[base + 3 * BLOCK];
    float4 b4 = t4[base + 4 * BLOCK];
    float4 b5 = t4[base + 5 * BLOCK];

    const float w0 = tw[j0];                    // block-uniform scalar loads
    const float w1 = tw[j0 + 1];

    float d0, d1, d2, d3;
    float s0 = 0.0f, s1 = 0.0f;

    d0 = a0.x - b0.x; d1 = a0.y - b0.y; d2 = a0.z - b0.z; d3 = a0.w - b0.w;
    s0 += d0 * d0 + d1 * d1 + d2 * d2 + d3 * d3;
    d0 = a1.x - b1.x; d1 = a1.y - b1.y; d2 = a1.z - b1.z; d3 = a1.w - b1.w;
    s0 += d0 * d0 + d1 * d1 + d2 * d2 + d3 * d3;
    d0 = a2.x - b2.x; d1 = a2.y - b2.y; d2 = a2.z - b2.z; d3 = a2.w - b2.w;
    s0 += d0 * d0 + d1 * d1 + d2 * d2 + d3 * d3;

    d0 = a3.x - b3.x; d1 = a3.y - b3.y; d2 = a3.z - b3.z; d3 = a3.w - b3.w;
    s1 += d0 * d0 + d1 * d1 + d2 * d2 + d3 * d3;
    d0 = a4.x - b4.x; d1 = a4.y - b4.y; d2 = a4.z - b4.z; d3 = a4.w - b4.w;
    s1 += d0 * d0 + d1 * d1 + d2 * d2 + d3 * d3;
    d0 = a5.x - b5.x; d1 = a5.y - b5.y; d2 = a5.z - b5.z; d3 = a5.w - b5.w;
    s1 += d0 * d0 + d1 * d1 + d2 * d2 + d3 * d3;

    float acc = w0 * w0 * s0 + w1 * w1 * s1;

    // wave64 shuffle reduction
    #pragma unroll
    for (int off = 32; off > 0; off >>= 1)
        acc += __shfl_down(acc, off, 64);

    __shared__ float lds[BLOCK / 64];
    int lane = threadIdx.x & 63;
    int wave = threadIdx.x >> 6;
    if (lane == 0) lds[wave] = acc;
    __syncthreads();

    if (threadIdx.x == 0) {
        float s = 0.0f;
        #pragma unroll
        for (int w_i = 0; w_i < BLOCK / 64; ++w_i) s += lds[w_i];
        partials[blockIdx.x] = s;
    }
}

// Kernel 2: reduce NBLOCKS1 partials, scale, write the scalar loss.
__global__ __launch_bounds__(BLOCK) void final_reduce_kernel(
    const float* __restrict__ partials,
    float* __restrict__ out)
{
    float acc = 0.0f;
    for (int i = threadIdx.x; i < NBLOCKS1; i += BLOCK)
        acc += partials[i];

    #pragma unroll
    for (int off = 32; off > 0; off >>= 1)
        acc += __shfl_down(acc, off, 64);

    __shared__ float lds[BLOCK / 64];
    int lane = threadIdx.x & 63;
    int wave = threadIdx.x >> 6;
    if (lane == 0) lds[wave] = acc;
    __syncthreads();

    if (threadIdx.x == 0) {
        float s = 0.0f;
        #pragma unroll
        for (int w_i = 0; w_i < BLOCK / 64; ++w_i) s += lds[w_i];
        out[0] = 0.5f * s / (float)N_TOTAL;
    }
}

extern "C" void kernel_launch(void* const* d_in, const int* in_sizes, int n_in,
                              void* d_out, int out_size, void* d_ws, size_t ws_size,
                              hipStream_t stream)
{
    const float* output = (const float*)d_in[0];   // [256,17,64,48] f32
    const float* target = (const float*)d_in[1];   // [256,17,64,48] f32
    const float* tw     = (const float*)d_in[2];   // [256,17,1]     f32

    float* partials = (float*)d_ws;                // NBLOCKS1 floats (8.5 KB)

    partial_sse_kernel<<<NBLOCKS1, BLOCK, 0, stream>>>(output, target, tw, partials);
    final_reduce_kernel<<<1, BLOCK, 0, stream>>>(partials, (float*)d_out);
}